// Round 2
// baseline (110.020 us; speedup 1.0000x reference)
//
#include <hip/hip_runtime.h>

// Bahdanau attention + LayerNorm + residual, B=8, TX=TY=128, D=H=512, fp32 in/out.
//
// Two kernels:
//   k1 gemm_all (bf16 MFMA 16x16x32, 32x64 tiles, 512 blocks = 2/CU,
//      in-kernel W transpose from fp32 [k][n], v_perm truncation fp32->bf16):
//        z=0: WcT[b][h][tx] = (ctx@Wa + bWa + bUa) * S   (transposed, prescaled)
//        z=1: Ux[row][h]    = (x@Ua) * S                 (S = 2*log2(e))
//   k2 attn2 (512 thr, 2 ty rows/block, 512 blocks = 2 blocks/CU):
//        scores -2*sum_h Va[h]/(1+exp2(WcT+Ux))
//        (tanh(v)=1-2/(1+e^{2v}); e^{2v}=2^{S v}; sumVa & bVa cancel in softmax)
//        -> softmax(tx) -> cv = attn@ctx -> LayerNorm*gamma+beta + x
//      2 blocks/CU so one block's score/cv phases hide the other's barrier /
//      softmax / LN bubbles. XCD-swizzled blockIdx pins each batch b to one
//      XCD (512 KB working set: WcT[b]+ctx[b] stays L2-hot despite 64
//      blocks/b re-reading it). ctx/xin/gamma/beta prefetch issued between
//      the s_part and s_at barriers (hides L2 latency under softmax).
// t [B,TY,TX,H] (268 MB) never materialized. Harness poison fills (2x 256 MiB,
// ~41 us each) dominate dur_us; addressable share ~27 us. Score phase floor:
// 134M trans ops / 19.7T = 6.8 us (v_exp+v_rcp, quarter-rate pipe).

#define SCALE 2.8853900817779268f   // 2*log2(e): e^{2v} == exp2(SCALE*v)

typedef __attribute__((ext_vector_type(8))) short short8;
typedef float floatx4 __attribute__((ext_vector_type(4)));

// Pack hi16(lo), hi16(hi) -> one u32 (bf16 truncation; err < 2^-8 rel, fine
// vs 0.142 abs threshold). v_perm_b32: sel 0-3 = s1 bytes, 4-7 = s0 bytes.
__device__ __forceinline__ unsigned pack_bf_trunc(float lo, float hi) {
  return __builtin_amdgcn_perm(__float_as_uint(hi), __float_as_uint(lo),
                               0x07060302u);
}

// ---------------------------------------------------------------------------
// k1: dual bf16-MFMA GEMM with inline B transpose+convert.
// C[1024,512] = A[1024,512] @ W[512,512]. 32x64 tile/block, BK=128, 4 K-iters.
// 512 thr = 8 waves as 2(m)x4(n); wave-tile 16x16, 4 MFMA / K-iter.
// Frag-major LDS slots (16B/lane): A slot s -> row=((s>>6)&1)*16+(s&15),
// k=(s>>7)*32+((s&63)>>4)*8; B slot s -> n=((s>>6)&3)*16+(s&15),
// k=(s>>8)*32+((s&63)>>4)*8. Conflict-free ds_read/write_b128.
// ---------------------------------------------------------------------------
__global__ __launch_bounds__(512) void gemm_all(
    const float* __restrict__ ctx, const float* __restrict__ xin,
    const float* __restrict__ Wa, const float* __restrict__ Ua,
    const float* __restrict__ bWa, const float* __restrict__ bUa,
    float* __restrict__ WcT, float* __restrict__ Ux) {
  const bool second = (blockIdx.z != 0);
  const float* __restrict__ A = second ? xin : ctx;
  const float* __restrict__ W = second ? Ua : Wa;   // [k][n] fp32
  const int m0 = blockIdx.x * 32, n0 = blockIdx.y * 64;

  __shared__ __align__(16) unsigned short As[512 * 8];    // 8 KB
  __shared__ __align__(16) unsigned short Bs[1024 * 8];   // 16 KB

  const int t = threadIdx.x;
  const int lane = t & 63, wv = t >> 6;

  // A staging: thread t fills A-slot t
  const int arow = ((t >> 6) & 1) * 16 + (t & 15);
  const int ak   = (t >> 7) * 32 + ((t & 63) >> 4) * 8;
  const float* aptr = A + (size_t)(m0 + arow) * 512 + ak;

  // B staging: thread t fills B-slots t and t+512
  const int bn0_ = ((t >> 6) & 3) * 16 + (t & 15);
  const int bk0_ = (t >> 8) * 32 + ((t & 63) >> 4) * 8;
  const int s2 = t + 512;
  const int bn1_ = ((s2 >> 6) & 3) * 16 + (s2 & 15);
  const int bk1_ = (s2 >> 8) * 32 + ((s2 & 63) >> 4) * 8;
  const float* bptr0 = W + (size_t)bk0_ * 512 + n0 + bn0_;
  const float* bptr1 = W + (size_t)bk1_ * 512 + n0 + bn1_;

  const int wm = wv & 1, wn = wv >> 1;   // 2x4 wave grid, wave-tile 16x16
  floatx4 acc = {};

  // register prefetch for kt=0
  float4 a0 = *(const float4*)(aptr);
  float4 a1 = *(const float4*)(aptr + 4);
  float bw0[8], bw1[8];
#pragma unroll
  for (int j = 0; j < 8; j++) {
    bw0[j] = bptr0[(size_t)j * 512];
    bw1[j] = bptr1[(size_t)j * 512];
  }

  for (int kt = 0; kt < 512; kt += 128) {
    union { short8 s; uint4 u; } av, bv0, bv1;
    av.u.x = pack_bf_trunc(a0.x, a0.y);
    av.u.y = pack_bf_trunc(a0.z, a0.w);
    av.u.z = pack_bf_trunc(a1.x, a1.y);
    av.u.w = pack_bf_trunc(a1.z, a1.w);
    bv0.u.x = pack_bf_trunc(bw0[0], bw0[1]);
    bv0.u.y = pack_bf_trunc(bw0[2], bw0[3]);
    bv0.u.z = pack_bf_trunc(bw0[4], bw0[5]);
    bv0.u.w = pack_bf_trunc(bw0[6], bw0[7]);
    bv1.u.x = pack_bf_trunc(bw1[0], bw1[1]);
    bv1.u.y = pack_bf_trunc(bw1[2], bw1[3]);
    bv1.u.z = pack_bf_trunc(bw1[4], bw1[5]);
    bv1.u.w = pack_bf_trunc(bw1[6], bw1[7]);
    ((short8*)As)[t] = av.s;
    ((short8*)Bs)[t] = bv0.s;
    ((short8*)Bs)[t + 512] = bv1.s;
    __syncthreads();
    if (kt + 128 < 512) {
      a0 = *(const float4*)(aptr + kt + 128);
      a1 = *(const float4*)(aptr + kt + 132);
      const float* p0 = bptr0 + (size_t)(kt + 128) * 512;
      const float* p1 = bptr1 + (size_t)(kt + 128) * 512;
#pragma unroll
      for (int j = 0; j < 8; j++) {
        bw0[j] = p0[(size_t)j * 512];
        bw1[j] = p1[(size_t)j * 512];
      }
    }
#pragma unroll
    for (int ks = 0; ks < 4; ks++) {
      const short8 af = ((const short8*)As)[ks * 128 + wm * 64 + lane];
      const short8 bf = ((const short8*)Bs)[ks * 256 + wn * 64 + lane];
      acc = __builtin_amdgcn_mfma_f32_16x16x32_bf16(af, bf, acc, 0, 0, 0);
    }
    __syncthreads();
  }

  // Epilogue. C/D: col = lane&15 (n), row = (lane>>4)*4 + r (m).
  const int quad = lane >> 4;
  const int h = n0 + wn * 16 + (lane & 15);
  const int mg0 = m0 + wm * 16 + quad * 4;
  if (!second) {
    const float bias = bWa[h] + bUa[h];
    const int b = mg0 >> 7, tx0 = mg0 & 127;
    float4 o;
    o.x = (acc[0] + bias) * SCALE;
    o.y = (acc[1] + bias) * SCALE;
    o.z = (acc[2] + bias) * SCALE;
    o.w = (acc[3] + bias) * SCALE;
    *(float4*)&WcT[(size_t)b * 65536 + (size_t)h * 128 + tx0] = o;
  } else {
#pragma unroll
    for (int r = 0; r < 4; r++)
      Ux[(size_t)(mg0 + r) * 512 + h] = acc[r] * SCALE;
  }
}

// ---------------------------------------------------------------------------
// k2: fused scores + softmax + cv + LayerNorm + residual.
// Block = (b, 2 ty rows), 512 threads, 512 blocks = 2 blocks/CU (4 waves/SIMD;
// second resident block hides barrier/softmax/LN bubbles of the first).
// Score: tx = t&127, h-quarter = t>>7 (128 hh iters, 2 rows each).
// cv/LN: d = t (all 512 threads), both rows per thread.
// ---------------------------------------------------------------------------
__global__ __launch_bounds__(512) void attn2(
    const float* __restrict__ WcT, const float* __restrict__ Ux,
    const float* __restrict__ ctx, const float* __restrict__ xin,
    const float* __restrict__ Va,
    const float* __restrict__ gamma, const float* __restrict__ beta,
    float* __restrict__ out) {
  // XCD swizzle: 512 blocks round-robin over 8 XCDs -> logical block
  // lb = (xcd)*64 + slot, so all 64 blocks of one b share an XCD's L2.
  const int lb = ((blockIdx.x & 7) << 6) | (blockIdx.x >> 3);
  const int b = lb >> 6;
  const int ty0 = (lb & 63) * 2;
  const int t = threadIdx.x;
  const int lane = t & 63, wv = t >> 6;

  __shared__ __align__(8) float2 s_ux[512];    // [h] -> rows 0..1 (prescaled)
  __shared__ float s_va[512];
  __shared__ float s_part[8][128];             // [hq*2+r][tx]
  __shared__ __align__(8) float2 s_at[128];    // attn weights [tx] -> rows
  __shared__ float s_red[2][2][8];             // [r][sum|sq][wave]
  __shared__ float s_mv[2][2];                 // [r][mean|rstd]

  {
    const float* uxb = Ux + (size_t)(b * 128 + ty0) * 512;
#pragma unroll
    for (int i = 0; i < 2; i++) {
      const int idx = t + i * 512;
      ((float*)&s_ux[idx & 511])[idx >> 9] = uxb[idx];
    }
    s_va[t] = Va[t];
  }
  __syncthreads();

  // ---- scores: thread owns (tx, h-quarter), 2 ty chains ----
  const int tx = t & 127, hq = t >> 7;
  {
    const float* wp = WcT + (size_t)b * 65536 + (size_t)hq * 16384 + tx;
    const float2* up = &s_ux[hq * 128];
    const float* vap = &s_va[hq * 128];
    float a0 = 0.f, a1 = 0.f;
#pragma unroll 4
    for (int hh = 0; hh < 128; hh++) {
      const float w = wp[(size_t)hh * 128];     // coalesced across tx
      const float2 u = up[hh];                  // b64 broadcast
      const float va = vap[hh];                 // b32 broadcast
      a0 = fmaf(va, __builtin_amdgcn_rcpf(1.0f + __builtin_amdgcn_exp2f(w + u.x)), a0);
      a1 = fmaf(va, __builtin_amdgcn_rcpf(1.0f + __builtin_amdgcn_exp2f(w + u.y)), a1);
    }
    s_part[hq * 2 + 0][tx] = a0;
    s_part[hq * 2 + 1][tx] = a1;
  }
  __syncthreads();

  // ---- prefetch (all waves) while waves 0-1 run softmax: ctx head chunk,
  //      residual x, gamma/beta. vmcnt only drained at first use after the
  //      next barrier, so softmax latency is covered by these loads. ----
  const int d = t;
  const float* cp = ctx + (size_t)b * 65536 + d;
  float cpre[8];
#pragma unroll
  for (int k = 0; k < 8; k++) cpre[k] = cp[(size_t)k * 512];
  const float g = gamma[d], bb = beta[d];
  const int row0 = b * 128 + ty0;
  const float xv0 = xin[(size_t)row0 * 512 + d];
  const float xv1 = xin[(size_t)(row0 + 1) * 512 + d];

  // ---- softmax: waves 0..1 -> ty rows 0..1 ----
  if (wv < 2) {
    const int r = wv;
    float sA = 0.f, sB = 0.f;
#pragma unroll
    for (int q = 0; q < 4; q++) {
      sA += s_part[q * 2 + r][lane];
      sB += s_part[q * 2 + r][lane + 64];
    }
    sA *= -2.0f; sB *= -2.0f;
    float m = fmaxf(sA, sB);
#pragma unroll
    for (int off = 32; off; off >>= 1) m = fmaxf(m, __shfl_xor(m, off));
    const float eA = __expf(sA - m);
    const float eB = __expf(sB - m);
    float sm = eA + eB;
#pragma unroll
    for (int off = 32; off; off >>= 1) sm += __shfl_xor(sm, off);
    const float inv = __builtin_amdgcn_rcpf(sm);
    ((float*)&s_at[lane])[r] = eA * inv;
    ((float*)&s_at[lane + 64])[r] = eB * inv;
  }
  __syncthreads();

  // ---- context vector: thread owns d, both rows ----
  float cv0 = 0.f, cv1 = 0.f;
#pragma unroll
  for (int k = 0; k < 8; k++) {
    const float2 at = s_at[k];
    cv0 = fmaf(at.x, cpre[k], cv0);
    cv1 = fmaf(at.y, cpre[k], cv1);
  }
#pragma unroll 4
  for (int x = 8; x < 128; x++) {
    const float c = cp[(size_t)x * 512];        // coalesced across d
    const float2 at = s_at[x];                  // b64 broadcast
    cv0 = fmaf(at.x, c, cv0);
    cv1 = fmaf(at.y, c, cv1);
  }

  // ---- layernorm stats: both rows reduced by every wave ----
  {
    float sm0 = cv0, q0 = cv0 * cv0, sm1 = cv1, q1 = cv1 * cv1;
#pragma unroll
    for (int off = 32; off; off >>= 1) {
      sm0 += __shfl_xor(sm0, off); q0 += __shfl_xor(q0, off);
      sm1 += __shfl_xor(sm1, off); q1 += __shfl_xor(q1, off);
    }
    if (lane == 0) {
      s_red[0][0][wv] = sm0; s_red[0][1][wv] = q0;
      s_red[1][0][wv] = sm1; s_red[1][1][wv] = q1;
    }
  }
  __syncthreads();
  if (t < 2) {
    float sm = 0.f, q = 0.f;
#pragma unroll
    for (int i = 0; i < 8; i++) { sm += s_red[t][0][i]; q += s_red[t][1][i]; }
    const float mean = sm * (1.0f / 512.0f);
    const float var = q * (1.0f / 512.0f) - mean * mean;
    s_mv[t][0] = mean;
    s_mv[t][1] = __builtin_amdgcn_rsqf(var + 1e-3f);  // keras LN eps
  }
  __syncthreads();

  // ---- normalize + gamma/beta + residual ----
  out[(size_t)row0 * 512 + d]       = (cv0 - s_mv[0][0]) * s_mv[0][1] * g + bb + xv0;
  out[(size_t)(row0 + 1) * 512 + d] = (cv1 - s_mv[1][0]) * s_mv[1][1] * g + bb + xv1;
}

extern "C" void kernel_launch(void* const* d_in, const int* in_sizes, int n_in,
                              void* d_out, int out_size, void* d_ws, size_t ws_size,
                              hipStream_t stream) {
  const float* ctx   = (const float*)d_in[0];
  const float* xin   = (const float*)d_in[1];
  const float* Wa    = (const float*)d_in[2];
  const float* bWa   = (const float*)d_in[3];
  const float* Ua    = (const float*)d_in[4];
  const float* bUa   = (const float*)d_in[5];
  const float* Va    = (const float*)d_in[6];
  // d_in[7] = bVa: additive constant on scores -> cancels in softmax.
  const float* gamma = (const float*)d_in[8];
  const float* beta  = (const float*)d_in[9];
  float* out = (float*)d_out;

  char* ws = (char*)d_ws;
  float* WcT = (float*)ws;                 // [8][512][128] fp32, 2 MB
  float* Ux  = (float*)(ws + (2u << 20));  // [1024][512]  fp32, 2 MB

  gemm_all<<<dim3(32, 8, 2), 512, 0, stream>>>(ctx, xin, Wa, Ua, bWa, bUa, WcT, Ux);
  attn2<<<512, 512, 0, stream>>>(WcT, Ux, ctx, xin, Va, gamma, beta, out);
}

// Round 3
// 108.464 us; speedup vs baseline: 1.0143x; 1.0143x over previous
//
#include <hip/hip_runtime.h>

// Bahdanau attention + LayerNorm + residual, B=8, TX=TY=128, D=H=512, fp32 in/out.
//
// Two kernels:
//   k1 gemm_all (bf16 MFMA 16x16x32, 32x64 tiles, 512 blocks = 2/CU,
//      in-kernel W transpose from fp32 [k][n], v_perm truncation fp32->bf16):
//        z=0: WcT[b][h2][tx] = packed bf16 pair {h=2*h2, 2*h2+1} of
//             (ctx@Wa + bWa + bUa) * S   (transposed, prescaled, RNE-rounded)
//        z=1: Ux[row][h]     = (x@Ua) * S  fp32        (S = 2*log2(e))
//   k2 attn4 (1024 thr, 4 ty rows/block, 256 blocks; cv/LN uses all threads):
//        scores -2*sum_h Va[h]/(1+exp2(WcT+Ux))
//        (tanh(v)=1-2/(1+e^{2v}); e^{2v}=2^{S v}; sumVa & bVa cancel in softmax)
//        -> softmax(tx) -> cv = attn@ctx -> LayerNorm*gamma+beta + x
//      Score loop reads WcT as u32 h-pairs: 1 load feeds 2h x 4rows = 16 trans
//      ops -> load-issue negligible; WcT L2 re-read traffic halved (64->32 MB).
// t [B,TY,TX,H] (268 MB) never materialized. Harness poison fills (2x 256 MiB,
// ~41 us each) dominate dur_us; addressable share ~27 us. Score phase floor:
// 134M trans ops / 19.7T = 6.8 us (v_exp+v_rcp, quarter-rate pipe).
// R1 lesson: 2-row/512-block split neutral (halved arith per load, 2x WcT L2).

#define SCALE 2.8853900817779268f   // 2*log2(e): e^{2v} == exp2(SCALE*v)

typedef __attribute__((ext_vector_type(8))) short short8;
typedef float floatx4 __attribute__((ext_vector_type(4)));

// Pack hi16(lo), hi16(hi) -> one u32 (bf16 truncation; err < 2^-8 rel, fine
// vs 0.142 abs threshold). v_perm_b32: sel 0-3 = s1 bytes, 4-7 = s0 bytes.
__device__ __forceinline__ unsigned pack_bf_trunc(float lo, float hi) {
  return __builtin_amdgcn_perm(__float_as_uint(hi), __float_as_uint(lo),
                               0x07060302u);
}

// RNE bf16 pack (used for the WcT quantization added this round: halves the
// rounding error on the exp2 argument vs truncation).
__device__ __forceinline__ unsigned pack_bf_rne(float lo, float hi) {
  unsigned ul = __float_as_uint(lo), uh = __float_as_uint(hi);
  ul += 0x7fffu + ((ul >> 16) & 1u);
  uh += 0x7fffu + ((uh >> 16) & 1u);
  return __builtin_amdgcn_perm(uh, ul, 0x07060302u);
}

// ---------------------------------------------------------------------------
// k1: dual bf16-MFMA GEMM with inline B transpose+convert.
// C[1024,512] = A[1024,512] @ W[512,512]. 32x64 tile/block, BK=128, 4 K-iters.
// 512 thr = 8 waves as 2(m)x4(n); wave-tile 16x16, 4 MFMA / K-iter.
// Frag-major LDS slots (16B/lane): A slot s -> row=((s>>6)&1)*16+(s&15),
// k=(s>>7)*32+((s&63)>>4)*8; B slot s -> n=((s>>6)&3)*16+(s&15),
// k=(s>>8)*32+((s&63)>>4)*8. Conflict-free ds_read/write_b128.
// ---------------------------------------------------------------------------
__global__ __launch_bounds__(512) void gemm_all(
    const float* __restrict__ ctx, const float* __restrict__ xin,
    const float* __restrict__ Wa, const float* __restrict__ Ua,
    const float* __restrict__ bWa, const float* __restrict__ bUa,
    unsigned* __restrict__ WcT, float* __restrict__ Ux) {
  const bool second = (blockIdx.z != 0);
  const float* __restrict__ A = second ? xin : ctx;
  const float* __restrict__ W = second ? Ua : Wa;   // [k][n] fp32
  const int m0 = blockIdx.x * 32, n0 = blockIdx.y * 64;

  __shared__ __align__(16) unsigned short As[512 * 8];    // 8 KB
  __shared__ __align__(16) unsigned short Bs[1024 * 8];   // 16 KB

  const int t = threadIdx.x;
  const int lane = t & 63, wv = t >> 6;

  // A staging: thread t fills A-slot t
  const int arow = ((t >> 6) & 1) * 16 + (t & 15);
  const int ak   = (t >> 7) * 32 + ((t & 63) >> 4) * 8;
  const float* aptr = A + (size_t)(m0 + arow) * 512 + ak;

  // B staging: thread t fills B-slots t and t+512
  const int bn0_ = ((t >> 6) & 3) * 16 + (t & 15);
  const int bk0_ = (t >> 8) * 32 + ((t & 63) >> 4) * 8;
  const int s2 = t + 512;
  const int bn1_ = ((s2 >> 6) & 3) * 16 + (s2 & 15);
  const int bk1_ = (s2 >> 8) * 32 + ((s2 & 63) >> 4) * 8;
  const float* bptr0 = W + (size_t)bk0_ * 512 + n0 + bn0_;
  const float* bptr1 = W + (size_t)bk1_ * 512 + n0 + bn1_;

  const int wm = wv & 1, wn = wv >> 1;   // 2x4 wave grid, wave-tile 16x16
  floatx4 acc = {};

  // register prefetch for kt=0
  float4 a0 = *(const float4*)(aptr);
  float4 a1 = *(const float4*)(aptr + 4);
  float bw0[8], bw1[8];
#pragma unroll
  for (int j = 0; j < 8; j++) {
    bw0[j] = bptr0[(size_t)j * 512];
    bw1[j] = bptr1[(size_t)j * 512];
  }

  for (int kt = 0; kt < 512; kt += 128) {
    union { short8 s; uint4 u; } av, bv0, bv1;
    av.u.x = pack_bf_trunc(a0.x, a0.y);
    av.u.y = pack_bf_trunc(a0.z, a0.w);
    av.u.z = pack_bf_trunc(a1.x, a1.y);
    av.u.w = pack_bf_trunc(a1.z, a1.w);
    bv0.u.x = pack_bf_trunc(bw0[0], bw0[1]);
    bv0.u.y = pack_bf_trunc(bw0[2], bw0[3]);
    bv0.u.z = pack_bf_trunc(bw0[4], bw0[5]);
    bv0.u.w = pack_bf_trunc(bw0[6], bw0[7]);
    bv1.u.x = pack_bf_trunc(bw1[0], bw1[1]);
    bv1.u.y = pack_bf_trunc(bw1[2], bw1[3]);
    bv1.u.z = pack_bf_trunc(bw1[4], bw1[5]);
    bv1.u.w = pack_bf_trunc(bw1[6], bw1[7]);
    ((short8*)As)[t] = av.s;
    ((short8*)Bs)[t] = bv0.s;
    ((short8*)Bs)[t + 512] = bv1.s;
    __syncthreads();
    if (kt + 128 < 512) {
      a0 = *(const float4*)(aptr + kt + 128);
      a1 = *(const float4*)(aptr + kt + 132);
      const float* p0 = bptr0 + (size_t)(kt + 128) * 512;
      const float* p1 = bptr1 + (size_t)(kt + 128) * 512;
#pragma unroll
      for (int j = 0; j < 8; j++) {
        bw0[j] = p0[(size_t)j * 512];
        bw1[j] = p1[(size_t)j * 512];
      }
    }
#pragma unroll
    for (int ks = 0; ks < 4; ks++) {
      const short8 af = ((const short8*)As)[ks * 128 + wm * 64 + lane];
      const short8 bf = ((const short8*)Bs)[ks * 256 + wn * 64 + lane];
      acc = __builtin_amdgcn_mfma_f32_16x16x32_bf16(af, bf, acc, 0, 0, 0);
    }
    __syncthreads();
  }

  // Epilogue. C/D: col = lane&15 (n), row = (lane>>4)*4 + r (m).
  const int quad = lane >> 4;
  const int h = n0 + wn * 16 + (lane & 15);
  const int mg0 = m0 + wm * 16 + quad * 4;
  if (!second) {
    // Pack (h even, h odd) bf16 pairs via lane-xor-1 exchange; even lanes
    // store uint4 (4 consecutive tx) at WcT[b][h>>1][tx0].
    const float bias = bWa[h] + bUa[h];
    const int b = mg0 >> 7, tx0 = mg0 & 127;
    unsigned pk[4];
#pragma unroll
    for (int r = 0; r < 4; r++) {
      const float v = (acc[r] + bias) * SCALE;
      const float vn = __shfl_xor(v, 1);     // odd lane's value (for even lanes)
      pk[r] = pack_bf_rne(v, vn);            // lo = even h, hi = odd h
    }
    if ((lane & 1) == 0) {
      uint4 o; o.x = pk[0]; o.y = pk[1]; o.z = pk[2]; o.w = pk[3];
      *(uint4*)&WcT[(size_t)b * 32768 + (size_t)(h >> 1) * 128 + tx0] = o;
    }
  } else {
#pragma unroll
    for (int r = 0; r < 4; r++)
      Ux[(size_t)(mg0 + r) * 512 + h] = acc[r] * SCALE;
  }
}

// ---------------------------------------------------------------------------
// k2: fused scores + softmax + cv + LayerNorm + residual.
// Block = (b, 4 ty rows), 1024 threads, 256 blocks (1/CU).
// Score: tx = t&127, h-eighth = t>>7; 32 u32 loads (h-pairs), 8 sigmoids each.
// cv/LN: d = t&511, row-pair = t>>9 (all threads busy).
// ---------------------------------------------------------------------------
__global__ __launch_bounds__(1024) void attn4(
    const unsigned* __restrict__ WcT, const float* __restrict__ Ux,
    const float* __restrict__ ctx, const float* __restrict__ xin,
    const float* __restrict__ Va,
    const float* __restrict__ gamma, const float* __restrict__ beta,
    float* __restrict__ out) {
  const int b = blockIdx.x >> 5;
  const int ty0 = (blockIdx.x & 31) * 4;
  const int t = threadIdx.x;
  const int lane = t & 63, wv = t >> 6;

  __shared__ __align__(16) float4 s_ux[512];   // [h] -> rows 0..3 (prescaled)
  __shared__ float s_va[512];
  __shared__ float s_part[32][128];            // [hq*4+r][tx]
  __shared__ __align__(16) float4 s_at[128];   // attn weights [tx] -> rows
  __shared__ float s_red[4][2][8];             // [r][sum|sq][wave-in-half]
  __shared__ float s_mv[4][2];                 // [r][mean|rstd]

  {
    const float* uxb = Ux + (size_t)(b * 128 + ty0) * 512;
    for (int i = t; i < 2048; i += 1024) {
      const int r = i >> 9, h = i & 511;
      ((float*)&s_ux[h])[r] = uxb[i];
    }
    if (t < 512) s_va[t] = Va[t];
  }
  __syncthreads();

  // ---- scores: thread owns (tx, h-eighth), 4 ty chains, bf16 h-pairs ----
  const int tx = t & 127, hq = t >> 7;
  {
    // h2 range [hq*32, hq*32+32), row stride 128 u32
    const unsigned* wp = WcT + (size_t)b * 32768 + (size_t)hq * 4096 + tx;
    float a0 = 0.f, a1 = 0.f, a2 = 0.f, a3 = 0.f;
#pragma unroll 4
    for (int hh = 0; hh < 32; hh++) {
      const unsigned u = wp[(size_t)hh * 128];          // coalesced across tx
      const float w0 = __uint_as_float(u << 16);        // h = hq*64 + 2*hh
      const float w1 = __uint_as_float(u & 0xffff0000u);// h+1
      const int h = hq * 64 + hh * 2;
      const float4 u0 = s_ux[h];
      const float4 u1 = s_ux[h + 1];
      const float va0 = s_va[h], va1 = s_va[h + 1];
      a0 = fmaf(va0, __builtin_amdgcn_rcpf(1.0f + __builtin_amdgcn_exp2f(w0 + u0.x)), a0);
      a1 = fmaf(va0, __builtin_amdgcn_rcpf(1.0f + __builtin_amdgcn_exp2f(w0 + u0.y)), a1);
      a2 = fmaf(va0, __builtin_amdgcn_rcpf(1.0f + __builtin_amdgcn_exp2f(w0 + u0.z)), a2);
      a3 = fmaf(va0, __builtin_amdgcn_rcpf(1.0f + __builtin_amdgcn_exp2f(w0 + u0.w)), a3);
      a0 = fmaf(va1, __builtin_amdgcn_rcpf(1.0f + __builtin_amdgcn_exp2f(w1 + u1.x)), a0);
      a1 = fmaf(va1, __builtin_amdgcn_rcpf(1.0f + __builtin_amdgcn_exp2f(w1 + u1.y)), a1);
      a2 = fmaf(va1, __builtin_amdgcn_rcpf(1.0f + __builtin_amdgcn_exp2f(w1 + u1.z)), a2);
      a3 = fmaf(va1, __builtin_amdgcn_rcpf(1.0f + __builtin_amdgcn_exp2f(w1 + u1.w)), a3);
    }
    s_part[hq * 4 + 0][tx] = a0;
    s_part[hq * 4 + 1][tx] = a1;
    s_part[hq * 4 + 2][tx] = a2;
    s_part[hq * 4 + 3][tx] = a3;
  }
  __syncthreads();

  // ---- softmax: waves 0..3 -> ty rows 0..3 ----
  if (wv < 4) {
    const int r = wv;
    float sA = 0.f, sB = 0.f;
#pragma unroll
    for (int q = 0; q < 8; q++) {
      sA += s_part[q * 4 + r][lane];
      sB += s_part[q * 4 + r][lane + 64];
    }
    sA *= -2.0f; sB *= -2.0f;
    float m = fmaxf(sA, sB);
#pragma unroll
    for (int off = 32; off; off >>= 1) m = fmaxf(m, __shfl_xor(m, off));
    const float eA = __expf(sA - m);
    const float eB = __expf(sB - m);
    float sm = eA + eB;
#pragma unroll
    for (int off = 32; off; off >>= 1) sm += __shfl_xor(sm, off);
    const float inv = __builtin_amdgcn_rcpf(sm);
    ((float*)&s_at[lane])[r] = eA * inv;
    ((float*)&s_at[lane + 64])[r] = eB * inv;
  }
  __syncthreads();

  // ---- context vector: thread owns (d = t&511, row-pair = t>>9) ----
  const int d = t & 511, rh = t >> 9;
  float cv0 = 0.f, cv1 = 0.f;
  {
    const float* cp = ctx + (size_t)b * 65536 + d;
#pragma unroll 4
    for (int x = 0; x < 128; x++) {
      const float c = cp[(size_t)x * 512];      // coalesced across d
      const float2 at = *(const float2*)((const float*)&s_at[x] + rh * 2);
      cv0 = fmaf(at.x, c, cv0);
      cv1 = fmaf(at.y, c, cv1);
    }
  }

  // ---- layernorm stats: rows rh*2, rh*2+1; waves 0-7 half rh=0, 8-15 rh=1
  const int wh = wv & 7;
#pragma unroll
  for (int j = 0; j < 2; j++) {
    const float v = j ? cv1 : cv0;
    float sm = v, q = v * v;
#pragma unroll
    for (int off = 32; off; off >>= 1) {
      sm += __shfl_xor(sm, off);
      q += __shfl_xor(q, off);
    }
    if (lane == 0) {
      s_red[rh * 2 + j][0][wh] = sm;
      s_red[rh * 2 + j][1][wh] = q;
    }
  }
  __syncthreads();
  if (t < 4) {
    float sm = 0.f, q = 0.f;
#pragma unroll
    for (int i = 0; i < 8; i++) { sm += s_red[t][0][i]; q += s_red[t][1][i]; }
    const float mean = sm * (1.0f / 512.0f);
    const float var = q * (1.0f / 512.0f) - mean * mean;
    s_mv[t][0] = mean;
    s_mv[t][1] = __builtin_amdgcn_rsqf(var + 1e-3f);  // keras LN eps
  }
  __syncthreads();

  // ---- normalize + gamma/beta + residual (2 rows per thread) ----
  {
    const float g = gamma[d], bb = beta[d];
#pragma unroll
    for (int j = 0; j < 2; j++) {
      const int r = rh * 2 + j;
      const int row = b * 128 + ty0 + r;
      const float v = j ? cv1 : cv0;
      const float xv = xin[(size_t)row * 512 + d];
      out[(size_t)row * 512 + d] = (v - s_mv[r][0]) * s_mv[r][1] * g + bb + xv;
    }
  }
}

extern "C" void kernel_launch(void* const* d_in, const int* in_sizes, int n_in,
                              void* d_out, int out_size, void* d_ws, size_t ws_size,
                              hipStream_t stream) {
  const float* ctx   = (const float*)d_in[0];
  const float* xin   = (const float*)d_in[1];
  const float* Wa    = (const float*)d_in[2];
  const float* bWa   = (const float*)d_in[3];
  const float* Ua    = (const float*)d_in[4];
  const float* bUa   = (const float*)d_in[5];
  const float* Va    = (const float*)d_in[6];
  // d_in[7] = bVa: additive constant on scores -> cancels in softmax.
  const float* gamma = (const float*)d_in[8];
  const float* beta  = (const float*)d_in[9];
  float* out = (float*)d_out;

  char* ws = (char*)d_ws;
  unsigned* WcT = (unsigned*)ws;           // [8][256][128] u32 (bf16 pairs), 1 MB
  float* Ux = (float*)(ws + (1u << 20));   // [1024][512] fp32, 2 MB

  gemm_all<<<dim3(32, 8, 2), 512, 0, stream>>>(ctx, xin, Wa, Ua, bWa, bUa, WcT, Ux);
  attn4<<<256, 1024, 0, stream>>>(WcT, Ux, ctx, xin, Va, gamma, beta, out);
}